// Round 5
// baseline (300.617 us; speedup 1.0000x reference)
//
#include <hip/hip_runtime.h>
#include <cmath>

#define NTOK 1024
#define HD   768
#define FF   3072
#define NE   8
#define NSLOT (NTOK * 2)
#define BK   64

typedef unsigned short u16;
typedef unsigned int   u32;
typedef __bf16 bf16x8 __attribute__((ext_vector_type(8)));
typedef float  f32x4  __attribute__((ext_vector_type(4)));

__device__ __forceinline__ u16 f2bf(float f) {
  union { float f; u32 u; } v; v.f = f;
  u32 r = v.u + 0x7FFFu + ((v.u >> 16) & 1u);
  return (u16)(r >> 16);
}

// global->LDS direct DMA, 16B per lane. LDS dest wave-uniform base; HW writes
// base + lane*16. Global address is per-lane (gather OK).
__device__ __forceinline__ void load16(const void* g, void* l) {
  __builtin_amdgcn_global_load_lds(
      (const __attribute__((address_space(1))) u32*)g,
      (__attribute__((address_space(3))) u32*)l, 16, 0, 0);
}

// ---------------------------------------------------------------------------
// Fused weight convert + transpose: fp32 [e][K][N] -> bf16 [e][N][K].
// z<8: w1 (K=HD, N=FF, n-tile=bx, k-tile=by). z>=8: w2 (K=FF, N=HD, swap).
// ---------------------------------------------------------------------------
__global__ __launch_bounds__(256) void convert_t_kernel(
    const float* __restrict__ w1, const float* __restrict__ w2,
    u16* __restrict__ w1t, u16* __restrict__ w2t)
{
  const int z = blockIdx.z;
  const float* src; u16* dst; int K, N, n0, k0;
  if (z < NE) {
    src = w1 + (size_t)z * HD * FF; dst = w1t + (size_t)z * FF * HD;
    K = HD; N = FF; n0 = blockIdx.x * 64; k0 = blockIdx.y * 64;
  } else {
    src = w2 + (size_t)(z - NE) * FF * HD; dst = w2t + (size_t)(z - NE) * HD * FF;
    K = FF; N = HD; n0 = blockIdx.y * 64; k0 = blockIdx.x * 64;
  }
  __shared__ u16 lt[64][65];
  const int tid = threadIdx.x;
  const int rr = tid >> 4;          // 0..15
  const int cc = (tid & 15) << 2;   // 0..60
#pragma unroll
  for (int j = 0; j < 4; ++j) {
    const int k = j * 16 + rr;
    const float4 v = *(const float4*)(src + (size_t)(k0 + k) * N + n0 + cc);
    lt[cc + 0][k] = f2bf(v.x); lt[cc + 1][k] = f2bf(v.y);
    lt[cc + 2][k] = f2bf(v.z); lt[cc + 3][k] = f2bf(v.w);
  }
  __syncthreads();
#pragma unroll
  for (int j = 0; j < 4; ++j) {
    const int n = j * 16 + rr;
    ushort4 o;
    o.x = lt[n][cc]; o.y = lt[n][cc + 1]; o.z = lt[n][cc + 2]; o.w = lt[n][cc + 3];
    *(ushort4*)(dst + (size_t)(n0 + n) * K + k0 + cc) = o;
  }
}

// ---------------------------------------------------------------------------
// Router stage A: one wave per token.
// ---------------------------------------------------------------------------
__global__ __launch_bounds__(256) void router_logits(
    const float* __restrict__ x, const float* __restrict__ rw,
    u16* __restrict__ xb, int* __restrict__ counts,
    int* __restrict__ ti, int* __restrict__ tpos, float* __restrict__ tg)
{
  __shared__ float rwt[NE * HD];
  const int tid = threadIdx.x;
  for (int i = tid; i < NE * HD; i += 256) {
    const int h = i >> 3, e = i & 7;
    rwt[e * HD + h] = rw[i];
  }
  __syncthreads();

  const int wid  = tid >> 6;
  const int lane = tid & 63;
  const int t    = blockIdx.x * 4 + wid;
  const float* xrow = x + (size_t)t * HD;
  u16* xbrow = xb + (size_t)t * HD;

  float acc[NE] = {};
#pragma unroll
  for (int j = 0; j < 12; ++j) {
    const int h = lane + j * 64;
    const float xv = xrow[h];
    xbrow[h] = f2bf(xv);
#pragma unroll
    for (int e = 0; e < NE; ++e) acc[e] += xv * rwt[e * HD + h];
  }
#pragma unroll
  for (int e = 0; e < NE; ++e) {
    float v = acc[e];
#pragma unroll
    for (int off = 32; off; off >>= 1) v += __shfl_down(v, off, 64);
    acc[e] = v;
  }

  if (lane == 0) {
    float v0 = -1e30f, v1 = -1e30f; int i0 = 0, i1 = 0;
#pragma unroll
    for (int e = 0; e < NE; ++e) {
      const float p = acc[e];
      if (p > v0) { v1 = v0; i1 = i0; v0 = p; i0 = e; }
      else if (p > v1) { v1 = p; i1 = e; }
    }
    const float e1 = expf(v1 - v0);
    const float g0 = 1.0f / (1.0f + e1);
    const float g1 = e1 / (1.0f + e1);
    const int p0 = atomicAdd(&counts[i0], 1);
    const int p1 = atomicAdd(&counts[i1], 1);
    ti[2 * t] = i0;  ti[2 * t + 1] = i1;
    tpos[2 * t] = p0; tpos[2 * t + 1] = p1;
    tg[2 * t] = g0;  tg[2 * t + 1] = g1;
  }
}

// ---------------------------------------------------------------------------
// Router stage B: prefix-sum counts -> seg, scatter slots.
// ---------------------------------------------------------------------------
__global__ __launch_bounds__(1024) void router_scatter(
    const int* __restrict__ counts, const int* __restrict__ ti,
    const int* __restrict__ tpos, const float* __restrict__ tg,
    int* __restrict__ tos, float* __restrict__ gos, int* __restrict__ seg)
{
  __shared__ int offs[NE];
  const int t = threadIdx.x;
  if (t == 0) {
    int o = 0;
    for (int e = 0; e < NE; ++e) {
      offs[e] = o; seg[e] = o; seg[NE + e] = counts[e]; o += counts[e];
    }
  }
  __syncthreads();
  const int i0 = ti[2 * t], i1 = ti[2 * t + 1];
  const int s0 = offs[i0] + tpos[2 * t];
  const int s1 = offs[i1] + tpos[2 * t + 1];
  tos[s0] = t; gos[s0] = tg[2 * t];
  tos[s1] = t; gos[s1] = tg[2 * t + 1];
}

// ---------------------------------------------------------------------------
// FFN GEMM core: 128x128 tile, BK=64, 4 waves (2x2, 64x64 each, 4x4 acc).
// global_load_lds staging (4 issues/wave/tile), XOR-swizzled unpadded LDS
// (physical 16B chunk p = logical c ^ (row&7)).
// ---------------------------------------------------------------------------

// FFN1: h = gelu(x_gather @ w1t[e]) -> hbuf (bf16)
__global__ __launch_bounds__(256) void ffn1_kernel(
    const u16* __restrict__ xb, const u16* __restrict__ w1t,
    const int* __restrict__ tos, const int* __restrict__ seg,
    u16* __restrict__ hbuf)
{
  const int e   = blockIdx.z;
  const int cnt = seg[NE + e];
  const int m0  = blockIdx.y * 128;
  if (m0 >= cnt) return;
  const int start = seg[e];
  const int n0    = blockIdx.x * 128;

  __shared__ __align__(16) u16 As[128 * 64];
  __shared__ __align__(16) u16 Bs[128 * 64];
  __shared__ int toks[128];

  const int tid = threadIdx.x;
  if (tid < 128) toks[tid] = tos[start + min(m0 + tid, cnt - 1)];
  __syncthreads();

  const int lane = tid & 63;
  const int wid  = tid >> 6;
  const int rsub = lane >> 3;           // 0..7 row within 8-row issue
  const int c8   = (lane & 7) ^ rsub;   // logical 16B chunk

  const u16* ag[4]; const u16* bg[4];
  u16 *al[4], *bl[4];
#pragma unroll
  for (int i = 0; i < 4; ++i) {
    const int rb = wid * 8 + i * 32;    // issue base row
    ag[i] = xb + (size_t)toks[rb + rsub] * HD + c8 * 8;
    bg[i] = w1t + ((size_t)e * FF + n0 + rb + rsub) * HD + c8 * 8;
    al[i] = As + rb * 64;
    bl[i] = Bs + rb * 64;
  }

  const int wm  = (wid >> 1) << 6;
  const int wn  = (wid & 1) << 6;
  const int q   = lane >> 4;
  const int r16 = lane & 15;

  f32x4 acc[4][4] = {};

  for (int k0 = 0; k0 < HD; k0 += BK) {
#pragma unroll
    for (int i = 0; i < 4; ++i) {
      load16(ag[i] + k0, al[i]);
      load16(bg[i] + k0, bl[i]);
    }
    __syncthreads();   // vmcnt(0) drain + barrier
#pragma unroll
    for (int s = 0; s < 2; ++s) {
      const int pa = ((s << 2) + q) ^ (r16 & 7);
      bf16x8 af[4], bf[4];
#pragma unroll
      for (int t = 0; t < 4; ++t)
        af[t] = *(const bf16x8*)(&As[(wm + t * 16 + r16) * 64 + pa * 8]);
#pragma unroll
      for (int t = 0; t < 4; ++t)
        bf[t] = *(const bf16x8*)(&Bs[(wn + t * 16 + r16) * 64 + pa * 8]);
#pragma unroll
      for (int t = 0; t < 4; ++t)
#pragma unroll
        for (int c = 0; c < 4; ++c)
          acc[t][c] = __builtin_amdgcn_mfma_f32_16x16x32_bf16(af[t], bf[c], acc[t][c], 0, 0, 0);
    }
    __syncthreads();
  }

#pragma unroll
  for (int t = 0; t < 4; ++t) {
    const int mbase = m0 + wm + t * 16 + q * 4;
#pragma unroll
    for (int i = 0; i < 4; ++i) {
      if (mbase + i < cnt) {
        u16* drow = hbuf + (size_t)(start + mbase + i) * FF + n0 + wn;
#pragma unroll
        for (int c = 0; c < 4; ++c) {
          float v = acc[t][c][i];
          v = 0.5f * v * (1.0f + erff(v * 0.70710678118f));
          drow[c * 16 + r16] = f2bf(v);
        }
      }
    }
  }
}

// FFN2: out += gate * (h @ w2t[e]), K-split x4, atomic fp32 accumulate.
#define KSPLIT 4
#define KSEG   (FF / KSPLIT)   // 768

__global__ __launch_bounds__(256) void ffn2_kernel(
    const u16* __restrict__ hbuf, const u16* __restrict__ w2t,
    const int* __restrict__ tos, const float* __restrict__ gos,
    const int* __restrict__ seg, float* __restrict__ out)
{
  const int ez  = blockIdx.z;
  const int e   = ez >> 2;
  const int ks  = ez & 3;
  const int cnt = seg[NE + e];
  const int m0  = blockIdx.y * 128;
  if (m0 >= cnt) return;
  const int start = seg[e];
  const int n0    = blockIdx.x * 128;
  const int kbase = ks * KSEG;

  __shared__ __align__(16) u16 As[128 * 64];
  __shared__ __align__(16) u16 Bs[128 * 64];
  __shared__ int   toks[128];
  __shared__ float gates[128];

  const int tid = threadIdx.x;
  if (tid < 128) {
    const int idx = start + min(m0 + tid, cnt - 1);
    toks[tid]  = tos[idx];
    gates[tid] = gos[idx];
  }
  __syncthreads();

  const int lane = tid & 63;
  const int wid  = tid >> 6;
  const int rsub = lane >> 3;
  const int c8   = (lane & 7) ^ rsub;

  const u16* ag[4]; const u16* bg[4];
  u16 *al[4], *bl[4];
#pragma unroll
  for (int i = 0; i < 4; ++i) {
    const int rb = wid * 8 + i * 32;
    ag[i] = hbuf + (size_t)(start + min(m0 + rb + rsub, cnt - 1)) * FF + kbase + c8 * 8;
    bg[i] = w2t + ((size_t)e * HD + n0 + rb + rsub) * FF + kbase + c8 * 8;
    al[i] = As + rb * 64;
    bl[i] = Bs + rb * 64;
  }

  const int wm  = (wid >> 1) << 6;
  const int wn  = (wid & 1) << 6;
  const int q   = lane >> 4;
  const int r16 = lane & 15;

  f32x4 acc[4][4] = {};

  for (int k0 = 0; k0 < KSEG; k0 += BK) {
#pragma unroll
    for (int i = 0; i < 4; ++i) {
      load16(ag[i] + k0, al[i]);
      load16(bg[i] + k0, bl[i]);
    }
    __syncthreads();
#pragma unroll
    for (int s = 0; s < 2; ++s) {
      const int pa = ((s << 2) + q) ^ (r16 & 7);
      bf16x8 af[4], bf[4];
#pragma unroll
      for (int t = 0; t < 4; ++t)
        af[t] = *(const bf16x8*)(&As[(wm + t * 16 + r16) * 64 + pa * 8]);
#pragma unroll
      for (int t = 0; t < 4; ++t)
        bf[t] = *(const bf16x8*)(&Bs[(wn + t * 16 + r16) * 64 + pa * 8]);
#pragma unroll
      for (int t = 0; t < 4; ++t)
#pragma unroll
        for (int c = 0; c < 4; ++c)
          acc[t][c] = __builtin_amdgcn_mfma_f32_16x16x32_bf16(af[t], bf[c], acc[t][c], 0, 0, 0);
    }
    __syncthreads();
  }

#pragma unroll
  for (int t = 0; t < 4; ++t) {
    const int mbase = wm + t * 16 + q * 4;
#pragma unroll
    for (int i = 0; i < 4; ++i) {
      const int mloc = mbase + i;
      if (m0 + mloc < cnt) {
        const int tok  = toks[mloc];
        const float g  = gates[mloc];
        float* drow = out + (size_t)tok * HD + n0 + wn;
#pragma unroll
        for (int c = 0; c < 4; ++c) {
          atomicAdd(drow + c * 16 + r16, g * acc[t][c][i]);
        }
      }
    }
  }
}

// ---------------------------------------------------------------------------
extern "C" void kernel_launch(void* const* d_in, const int* in_sizes, int n_in,
                              void* d_out, int out_size, void* d_ws, size_t ws_size,
                              hipStream_t stream) {
  const float* x  = (const float*)d_in[0];
  const float* rw = (const float*)d_in[1];
  const float* w1 = (const float*)d_in[2];
  const float* w2 = (const float*)d_in[3];
  float* out = (float*)d_out;

  char* ws = (char*)d_ws;
  const size_t o_xb    = 0;
  const size_t o_hbuf  = o_xb + (size_t)NTOK * HD * 2;
  const size_t o_tos   = o_hbuf + (size_t)NSLOT * FF * 2;
  const size_t o_gos   = o_tos + (size_t)NSLOT * 4;
  const size_t o_seg   = o_gos + (size_t)NSLOT * 4;
  const size_t o_cnt   = o_seg + 64 * 4;
  const size_t o_ti    = o_cnt + NE * 4;
  const size_t o_tpos  = o_ti + (size_t)NSLOT * 4;
  const size_t o_tg    = o_tpos + (size_t)NSLOT * 4;
  const size_t o_w1t   = (o_tg + (size_t)NSLOT * 4 + 255) & ~(size_t)255;
  const size_t o_w2t   = o_w1t + (size_t)NE * HD * FF * 2;
  u16*   xb    = (u16*)(ws + o_xb);
  u16*   hbuf  = (u16*)(ws + o_hbuf);
  int*   tos   = (int*)(ws + o_tos);
  float* gos   = (float*)(ws + o_gos);
  int*   seg   = (int*)(ws + o_seg);
  int*   cnts  = (int*)(ws + o_cnt);
  int*   ti    = (int*)(ws + o_ti);
  int*   tpos  = (int*)(ws + o_tpos);
  float* tg    = (float*)(ws + o_tg);
  u16*   w1t   = (u16*)(ws + o_w1t);
  u16*   w2t   = (u16*)(ws + o_w2t);

  hipMemsetAsync(d_out, 0, (size_t)NTOK * HD * sizeof(float), stream);
  hipMemsetAsync(cnts, 0, NE * sizeof(int), stream);
  hipLaunchKernelGGL(convert_t_kernel, dim3(48, 12, 2 * NE), dim3(256), 0, stream,
                     w1, w2, w1t, w2t);
  hipLaunchKernelGGL(router_logits, dim3(NTOK / 4), dim3(256), 0, stream,
                     x, rw, xb, cnts, ti, tpos, tg);
  hipLaunchKernelGGL(router_scatter, dim3(1), dim3(1024), 0, stream,
                     cnts, ti, tpos, tg, tos, gos, seg);
  hipLaunchKernelGGL(ffn1_kernel, dim3(FF / 128, NTOK / 128, NE), dim3(256), 0, stream,
                     xb, w1t, tos, seg, hbuf);
  hipLaunchKernelGGL(ffn2_kernel, dim3(HD / 128, NTOK / 128, NE * KSPLIT), dim3(256), 0, stream,
                     hbuf, w2t, tos, gos, seg, out);
}

// Round 6
// 281.394 us; speedup vs baseline: 1.0683x; 1.0683x over previous
//
#include <hip/hip_runtime.h>
#include <cmath>

#define NTOK 1024
#define HD   768
#define FF   3072
#define NE   8
#define NSLOT (NTOK * 2)
#define BK   64

typedef unsigned short u16;
typedef unsigned int   u32;
typedef __bf16 bf16x8 __attribute__((ext_vector_type(8)));
typedef float  f32x4  __attribute__((ext_vector_type(4)));
typedef u16    u16x8  __attribute__((ext_vector_type(8)));

__device__ __forceinline__ u16 f2bf(float f) {
  union { float f; u32 u; } v; v.f = f;
  u32 r = v.u + 0x7FFFu + ((v.u >> 16) & 1u);
  return (u16)(r >> 16);
}

// global->LDS direct DMA, 16B per lane. LDS dest wave-uniform base; HW writes
// base + lane*16. Global address is per-lane (gather OK).
__device__ __forceinline__ void load16(const void* g, void* l) {
  __builtin_amdgcn_global_load_lds(
      (const __attribute__((address_space(1))) u32*)g,
      (__attribute__((address_space(3))) u32*)l, 16, 0, 0);
}

// ---------------------------------------------------------------------------
// Weight convert + transpose: fp32 [e][K][N] -> bf16 [e][N][K].
// 128k x 64n tile per block. Reads float4 coalesced; writes ushort8 (16B/lane,
// 256B contiguous per 8 lanes). LDS [n][k] row stride 130 u16 (write-phase
// bank step 4 -> 2-way, free).
// z<8: w1 (K=HD: 6 k-tiles x 48 n-tiles). z>=8: w2 (K=FF: 24 k-tiles x 12 n).
// ---------------------------------------------------------------------------
#define CLD 130

__global__ __launch_bounds__(256) void convert_t_kernel(
    const float* __restrict__ w1, const float* __restrict__ w2,
    u16* __restrict__ w1t, u16* __restrict__ w2t)
{
  const int z = blockIdx.z;
  const float* src; u16* dst; int K, N, n0, k0;
  if (z < NE) {
    src = w1 + (size_t)z * HD * FF;  dst = w1t + (size_t)z * FF * HD;
    K = HD; N = FF;
    n0 = blockIdx.x * 64;
    k0 = blockIdx.y * 128;
  } else {
    src = w2 + (size_t)(z - NE) * FF * HD;  dst = w2t + (size_t)(z - NE) * HD * FF;
    K = FF; N = HD;
    k0 = (blockIdx.x % 24) * 128;
    n0 = (blockIdx.y * 2 + blockIdx.x / 24) * 64;
  }
  __shared__ u16 lt[64 * CLD];   // [n][k], 16.6 KB
  const int tid = threadIdx.x;
  const int rr = tid >> 4;          // k sub-row 0..15
  const int cc = (tid & 15) << 2;   // n 0..60
#pragma unroll
  for (int j = 0; j < 8; ++j) {
    const int k = j * 16 + rr;
    const float4 v = *(const float4*)(src + (size_t)(k0 + k) * N + n0 + cc);
    lt[(cc + 0) * CLD + k] = f2bf(v.x); lt[(cc + 1) * CLD + k] = f2bf(v.y);
    lt[(cc + 2) * CLD + k] = f2bf(v.z); lt[(cc + 3) * CLD + k] = f2bf(v.w);
  }
  __syncthreads();
  const int wn = tid >> 3;          // n row 0..31 (+32 second pass)
  const int kc = (tid & 7) << 4;    // k chunk 0..112
#pragma unroll
  for (int pass = 0; pass < 2; ++pass) {
    const int n = wn + pass * 32;
    u16x8 a, b;
#pragma unroll
    for (int d = 0; d < 8; ++d) a[d] = lt[n * CLD + kc + d];
#pragma unroll
    for (int d = 0; d < 8; ++d) b[d] = lt[n * CLD + kc + 8 + d];
    u16* drow = dst + (size_t)(n0 + n) * K + k0 + kc;
    *(u16x8*)(drow)     = a;
    *(u16x8*)(drow + 8) = b;
  }
}

// ---------------------------------------------------------------------------
// Router stage A: one wave per token.
// ---------------------------------------------------------------------------
__global__ __launch_bounds__(256) void router_logits(
    const float* __restrict__ x, const float* __restrict__ rw,
    u16* __restrict__ xb, int* __restrict__ counts,
    int* __restrict__ ti, int* __restrict__ tpos, float* __restrict__ tg)
{
  __shared__ float rwt[NE * HD];
  const int tid = threadIdx.x;
  for (int i = tid; i < NE * HD; i += 256) {
    const int h = i >> 3, e = i & 7;
    rwt[e * HD + h] = rw[i];
  }
  __syncthreads();

  const int wid  = tid >> 6;
  const int lane = tid & 63;
  const int t    = blockIdx.x * 4 + wid;
  const float* xrow = x + (size_t)t * HD;
  u16* xbrow = xb + (size_t)t * HD;

  float acc[NE] = {};
#pragma unroll
  for (int j = 0; j < 12; ++j) {
    const int h = lane + j * 64;
    const float xv = xrow[h];
    xbrow[h] = f2bf(xv);
#pragma unroll
    for (int e = 0; e < NE; ++e) acc[e] += xv * rwt[e * HD + h];
  }
#pragma unroll
  for (int e = 0; e < NE; ++e) {
    float v = acc[e];
#pragma unroll
    for (int off = 32; off; off >>= 1) v += __shfl_down(v, off, 64);
    acc[e] = v;
  }

  if (lane == 0) {
    float v0 = -1e30f, v1 = -1e30f; int i0 = 0, i1 = 0;
#pragma unroll
    for (int e = 0; e < NE; ++e) {
      const float p = acc[e];
      if (p > v0) { v1 = v0; i1 = i0; v0 = p; i0 = e; }
      else if (p > v1) { v1 = p; i1 = e; }
    }
    const float e1 = expf(v1 - v0);
    const float g0 = 1.0f / (1.0f + e1);
    const float g1 = e1 / (1.0f + e1);
    const int p0 = atomicAdd(&counts[i0], 1);
    const int p1 = atomicAdd(&counts[i1], 1);
    ti[2 * t] = i0;  ti[2 * t + 1] = i1;
    tpos[2 * t] = p0; tpos[2 * t + 1] = p1;
    tg[2 * t] = g0;  tg[2 * t + 1] = g1;
  }
}

// ---------------------------------------------------------------------------
// Router stage B: prefix-sum counts -> seg, scatter slots.
// ---------------------------------------------------------------------------
__global__ __launch_bounds__(1024) void router_scatter(
    const int* __restrict__ counts, const int* __restrict__ ti,
    const int* __restrict__ tpos, const float* __restrict__ tg,
    int* __restrict__ tos, float* __restrict__ gos, int* __restrict__ seg)
{
  __shared__ int offs[NE];
  const int t = threadIdx.x;
  if (t == 0) {
    int o = 0;
    for (int e = 0; e < NE; ++e) {
      offs[e] = o; seg[e] = o; seg[NE + e] = counts[e]; o += counts[e];
    }
  }
  __syncthreads();
  const int i0 = ti[2 * t], i1 = ti[2 * t + 1];
  const int s0 = offs[i0] + tpos[2 * t];
  const int s1 = offs[i1] + tpos[2 * t + 1];
  tos[s0] = t; gos[s0] = tg[2 * t];
  tos[s1] = t; gos[s1] = tg[2 * t + 1];
}

// ---------------------------------------------------------------------------
// FFN GEMM core: 128m x 64n tile, BK=64, 4 waves (2x2 over 64x32 each,
// acc 4x2). global_load_lds staging (A:4 + B:2 issues/wave), XOR-swizzled
// unpadded LDS (physical 16B chunk = logical ^ (row&7)).
// ---------------------------------------------------------------------------

// FFN1: h = gelu(x_gather @ w1t[e]) -> hbuf (bf16)
__global__ __launch_bounds__(256) void ffn1_kernel(
    const u16* __restrict__ xb, const u16* __restrict__ w1t,
    const int* __restrict__ tos, const int* __restrict__ seg,
    u16* __restrict__ hbuf)
{
  const int e   = blockIdx.z;
  const int cnt = seg[NE + e];
  const int m0  = blockIdx.y * 128;
  if (m0 >= cnt) return;
  const int start = seg[e];
  const int n0    = blockIdx.x * 64;

  __shared__ __align__(16) u16 As[128 * 64];
  __shared__ __align__(16) u16 Bs[64 * 64];
  __shared__ int toks[128];

  const int tid = threadIdx.x;
  if (tid < 128) toks[tid] = tos[start + min(m0 + tid, cnt - 1)];
  __syncthreads();

  const int lane = tid & 63;
  const int wid  = tid >> 6;
  const int rsub = lane >> 3;           // 0..7
  const int c8   = (lane & 7) ^ rsub;   // logical 16B chunk

  const u16* ag[4]; u16* al[4];
#pragma unroll
  for (int i = 0; i < 4; ++i) {
    const int rb = wid * 8 + i * 32;
    ag[i] = xb + (size_t)toks[rb + rsub] * HD + c8 * 8;
    al[i] = As + rb * 64;
  }
  const u16* bg[2]; u16* bl[2];
#pragma unroll
  for (int i = 0; i < 2; ++i) {
    const int rb = wid * 8 + i * 32;
    bg[i] = w1t + ((size_t)e * FF + n0 + rb + rsub) * HD + c8 * 8;
    bl[i] = Bs + rb * 64;
  }

  const int wm  = (wid >> 1) << 6;      // 0 / 64
  const int wn  = (wid & 1) << 5;       // 0 / 32
  const int q   = lane >> 4;
  const int r16 = lane & 15;

  f32x4 acc[4][2] = {};

  for (int k0 = 0; k0 < HD; k0 += BK) {
#pragma unroll
    for (int i = 0; i < 4; ++i) load16(ag[i] + k0, al[i]);
#pragma unroll
    for (int i = 0; i < 2; ++i) load16(bg[i] + k0, bl[i]);
    __syncthreads();
#pragma unroll
    for (int s = 0; s < 2; ++s) {
      const int pa = ((s << 2) + q) ^ (r16 & 7);
      bf16x8 af[4], bf[2];
#pragma unroll
      for (int t = 0; t < 4; ++t)
        af[t] = *(const bf16x8*)(&As[(wm + t * 16 + r16) * 64 + pa * 8]);
#pragma unroll
      for (int t = 0; t < 2; ++t)
        bf[t] = *(const bf16x8*)(&Bs[(wn + t * 16 + r16) * 64 + pa * 8]);
#pragma unroll
      for (int t = 0; t < 4; ++t)
#pragma unroll
        for (int c = 0; c < 2; ++c)
          acc[t][c] = __builtin_amdgcn_mfma_f32_16x16x32_bf16(af[t], bf[c], acc[t][c], 0, 0, 0);
    }
    __syncthreads();
  }

#pragma unroll
  for (int t = 0; t < 4; ++t) {
    const int mbase = m0 + wm + t * 16 + q * 4;
#pragma unroll
    for (int i = 0; i < 4; ++i) {
      if (mbase + i < cnt) {
        u16* drow = hbuf + (size_t)(start + mbase + i) * FF + n0 + wn;
#pragma unroll
        for (int c = 0; c < 2; ++c) {
          float v = acc[t][c][i];
          v = 0.5f * v * (1.0f + erff(v * 0.70710678118f));
          drow[c * 16 + r16] = f2bf(v);
        }
      }
    }
  }
}

// FFN2: out += gate * (h @ w2t[e]), K-split x4, atomic fp32 accumulate.
#define KSPLIT 4
#define KSEG   (FF / KSPLIT)   // 768

__global__ __launch_bounds__(256) void ffn2_kernel(
    const u16* __restrict__ hbuf, const u16* __restrict__ w2t,
    const int* __restrict__ tos, const float* __restrict__ gos,
    const int* __restrict__ seg, float* __restrict__ out)
{
  const int ez  = blockIdx.z;
  const int e   = ez >> 2;
  const int ks  = ez & 3;
  const int cnt = seg[NE + e];
  const int m0  = blockIdx.y * 128;
  if (m0 >= cnt) return;
  const int start = seg[e];
  const int n0    = blockIdx.x * 64;
  const int kbase = ks * KSEG;

  __shared__ __align__(16) u16 As[128 * 64];
  __shared__ __align__(16) u16 Bs[64 * 64];
  __shared__ int   toks[128];
  __shared__ float gates[128];

  const int tid = threadIdx.x;
  if (tid < 128) {
    const int idx = start + min(m0 + tid, cnt - 1);
    toks[tid]  = tos[idx];
    gates[tid] = gos[idx];
  }
  __syncthreads();

  const int lane = tid & 63;
  const int wid  = tid >> 6;
  const int rsub = lane >> 3;
  const int c8   = (lane & 7) ^ rsub;

  const u16* ag[4]; u16* al[4];
#pragma unroll
  for (int i = 0; i < 4; ++i) {
    const int rb = wid * 8 + i * 32;
    ag[i] = hbuf + (size_t)(start + min(m0 + rb + rsub, cnt - 1)) * FF + kbase + c8 * 8;
    al[i] = As + rb * 64;
  }
  const u16* bg[2]; u16* bl[2];
#pragma unroll
  for (int i = 0; i < 2; ++i) {
    const int rb = wid * 8 + i * 32;
    bg[i] = w2t + ((size_t)e * HD + n0 + rb + rsub) * FF + kbase + c8 * 8;
    bl[i] = Bs + rb * 64;
  }

  const int wm  = (wid >> 1) << 6;
  const int wn  = (wid & 1) << 5;
  const int q   = lane >> 4;
  const int r16 = lane & 15;

  f32x4 acc[4][2] = {};

  for (int k0 = 0; k0 < KSEG; k0 += BK) {
#pragma unroll
    for (int i = 0; i < 4; ++i) load16(ag[i] + k0, al[i]);
#pragma unroll
    for (int i = 0; i < 2; ++i) load16(bg[i] + k0, bl[i]);
    __syncthreads();
#pragma unroll
    for (int s = 0; s < 2; ++s) {
      const int pa = ((s << 2) + q) ^ (r16 & 7);
      bf16x8 af[4], bf[2];
#pragma unroll
      for (int t = 0; t < 4; ++t)
        af[t] = *(const bf16x8*)(&As[(wm + t * 16 + r16) * 64 + pa * 8]);
#pragma unroll
      for (int t = 0; t < 2; ++t)
        bf[t] = *(const bf16x8*)(&Bs[(wn + t * 16 + r16) * 64 + pa * 8]);
#pragma unroll
      for (int t = 0; t < 4; ++t)
#pragma unroll
        for (int c = 0; c < 2; ++c)
          acc[t][c] = __builtin_amdgcn_mfma_f32_16x16x32_bf16(af[t], bf[c], acc[t][c], 0, 0, 0);
    }
    __syncthreads();
  }

#pragma unroll
  for (int t = 0; t < 4; ++t) {
    const int mbase = wm + t * 16 + q * 4;
#pragma unroll
    for (int i = 0; i < 4; ++i) {
      const int mloc = mbase + i;
      if (m0 + mloc < cnt) {
        const int tok  = toks[mloc];
        const float g  = gates[mloc];
        float* drow = out + (size_t)tok * HD + n0 + wn;
#pragma unroll
        for (int c = 0; c < 2; ++c) {
          atomicAdd(drow + c * 16 + r16, g * acc[t][c][i]);
        }
      }
    }
  }
}

// ---------------------------------------------------------------------------
extern "C" void kernel_launch(void* const* d_in, const int* in_sizes, int n_in,
                              void* d_out, int out_size, void* d_ws, size_t ws_size,
                              hipStream_t stream) {
  const float* x  = (const float*)d_in[0];
  const float* rw = (const float*)d_in[1];
  const float* w1 = (const float*)d_in[2];
  const float* w2 = (const float*)d_in[3];
  float* out = (float*)d_out;

  char* ws = (char*)d_ws;
  const size_t o_xb    = 0;
  const size_t o_hbuf  = o_xb + (size_t)NTOK * HD * 2;
  const size_t o_tos   = o_hbuf + (size_t)NSLOT * FF * 2;
  const size_t o_gos   = o_tos + (size_t)NSLOT * 4;
  const size_t o_seg   = o_gos + (size_t)NSLOT * 4;
  const size_t o_cnt   = o_seg + 64 * 4;
  const size_t o_ti    = o_cnt + NE * 4;
  const size_t o_tpos  = o_ti + (size_t)NSLOT * 4;
  const size_t o_tg    = o_tpos + (size_t)NSLOT * 4;
  const size_t o_w1t   = (o_tg + (size_t)NSLOT * 4 + 255) & ~(size_t)255;
  const size_t o_w2t   = o_w1t + (size_t)NE * HD * FF * 2;
  u16*   xb    = (u16*)(ws + o_xb);
  u16*   hbuf  = (u16*)(ws + o_hbuf);
  int*   tos   = (int*)(ws + o_tos);
  float* gos   = (float*)(ws + o_gos);
  int*   seg   = (int*)(ws + o_seg);
  int*   cnts  = (int*)(ws + o_cnt);
  int*   ti    = (int*)(ws + o_ti);
  int*   tpos  = (int*)(ws + o_tpos);
  float* tg    = (float*)(ws + o_tg);
  u16*   w1t   = (u16*)(ws + o_w1t);
  u16*   w2t   = (u16*)(ws + o_w2t);

  hipMemsetAsync(d_out, 0, (size_t)NTOK * HD * sizeof(float), stream);
  hipMemsetAsync(cnts, 0, NE * sizeof(int), stream);
  hipLaunchKernelGGL(convert_t_kernel, dim3(48, 6, 2 * NE), dim3(256), 0, stream,
                     w1, w2, w1t, w2t);
  hipLaunchKernelGGL(router_logits, dim3(NTOK / 4), dim3(256), 0, stream,
                     x, rw, xb, cnts, ti, tpos, tg);
  hipLaunchKernelGGL(router_scatter, dim3(1), dim3(1024), 0, stream,
                     cnts, ti, tpos, tg, tos, gos, seg);
  hipLaunchKernelGGL(ffn1_kernel, dim3(FF / 64, NTOK / 128, NE), dim3(256), 0, stream,
                     xb, w1t, tos, seg, hbuf);
  hipLaunchKernelGGL(ffn2_kernel, dim3(HD / 64, NTOK / 128, NE * KSPLIT), dim3(256), 0, stream,
                     hbuf, w2t, tos, gos, seg, out);
}

// Round 7
// 270.597 us; speedup vs baseline: 1.1109x; 1.0399x over previous
//
#include <hip/hip_runtime.h>
#include <cmath>

#define NTOK 1024
#define HD   768
#define FF   3072
#define NE   8
#define NSLOT (NTOK * 2)
#define BK   64
#define CLD  130
#define NB_CONV 4608   // 16 matrices-halves * 288 tiles

typedef unsigned short u16;
typedef unsigned int   u32;
typedef __bf16 bf16x8 __attribute__((ext_vector_type(8)));
typedef float  f32x4  __attribute__((ext_vector_type(4)));
typedef u16    u16x8  __attribute__((ext_vector_type(8)));

__device__ __forceinline__ u16 f2bf(float f) {
  union { float f; u32 u; } v; v.f = f;
  u32 r = v.u + 0x7FFFu + ((v.u >> 16) & 1u);
  return (u16)(r >> 16);
}

// global->LDS direct DMA, 16B per lane. LDS dest wave-uniform base; HW writes
// base + lane*16. Global address is per-lane (gather OK).
__device__ __forceinline__ void load16(const void* g, void* l) {
  __builtin_amdgcn_global_load_lds(
      (const __attribute__((address_space(1))) u32*)g,
      (__attribute__((address_space(3))) u32*)l, 16, 0, 0);
}

// ---------------------------------------------------------------------------
// Fused kernel: blocks [0, NB_CONV) = weight convert+transpose,
// blocks [NB_CONV, NB_CONV+256) = router logits/top2 (independent work).
//
// Convert: fp32 [e][K][N] -> bf16 [e][N][K], 128k x 64n tile.
// Write phase: each store instr covers 4 FULL 256B row segments (no partial
// sectors -> no fetch-on-write, single writeback per line).
// ---------------------------------------------------------------------------
__global__ __launch_bounds__(256) void convert_router_kernel(
    const float* __restrict__ w1, const float* __restrict__ w2,
    u16* __restrict__ w1t, u16* __restrict__ w2t,
    const float* __restrict__ x, const float* __restrict__ rw,
    u16* __restrict__ xb, int* __restrict__ counts,
    int* __restrict__ ti, int* __restrict__ tpos, float* __restrict__ tg)
{
  __shared__ char smem[NE * HD * 4];   // 24576 B (router); convert uses 16640 B
  const int tid  = threadIdx.x;
  const int lane = tid & 63;
  const int wid  = tid >> 6;

  if (blockIdx.x < NB_CONV) {
    // ---------------- convert path ----------------
    const int z   = blockIdx.x / 288;
    const int rem = blockIdx.x % 288;
    const float* src; u16* dst; int K, N, n0, k0;
    if (z < NE) {
      src = w1 + (size_t)z * HD * FF;  dst = w1t + (size_t)z * FF * HD;
      K = HD; N = FF;
      n0 = (rem % 48) * 64;  k0 = (rem / 48) * 128;
    } else {
      src = w2 + (size_t)(z - NE) * FF * HD;  dst = w2t + (size_t)(z - NE) * HD * FF;
      K = FF; N = HD;
      k0 = (rem % 24) * 128; n0 = (rem / 24) * 64;
    }
    u16* lt = (u16*)smem;             // [64 n][CLD k]
    const int rr = tid >> 4;          // k sub-row 0..15
    const int cc = (tid & 15) << 2;   // n 0..60
#pragma unroll
    for (int j = 0; j < 8; ++j) {
      const int k = j * 16 + rr;
      const float4 v = *(const float4*)(src + (size_t)(k0 + k) * N + n0 + cc);
      lt[(cc + 0) * CLD + k] = f2bf(v.x); lt[(cc + 1) * CLD + k] = f2bf(v.y);
      lt[(cc + 2) * CLD + k] = f2bf(v.z); lt[(cc + 3) * CLD + k] = f2bf(v.w);
    }
    __syncthreads();
    const int l15 = lane & 15;        // 16B chunk within row (k)
    const int r4  = lane >> 4;        // row within 4-row group
#pragma unroll
    for (int s = 0; s < 4; ++s) {
      const int r = wid * 16 + s * 4 + r4;   // n row 0..63
      u16x8 v;
#pragma unroll
      for (int d = 0; d < 8; ++d) v[d] = lt[r * CLD + l15 * 8 + d];
      *(u16x8*)(dst + (size_t)(n0 + r) * K + k0 + l15 * 8) = v;
    }
  } else {
    // ---------------- router path ----------------
    float* rwt = (float*)smem;        // [e][h]
    for (int i = tid; i < NE * HD; i += 256) {
      const int h = i >> 3, e = i & 7;
      rwt[e * HD + h] = rw[i];
    }
    __syncthreads();

    const int t = (blockIdx.x - NB_CONV) * 4 + wid;
    const float* xrow = x + (size_t)t * HD;
    u16* xbrow = xb + (size_t)t * HD;

    float acc[NE] = {};
#pragma unroll
    for (int j = 0; j < 12; ++j) {
      const int h = lane + j * 64;
      const float xv = xrow[h];
      xbrow[h] = f2bf(xv);
#pragma unroll
      for (int e = 0; e < NE; ++e) acc[e] += xv * rwt[e * HD + h];
    }
#pragma unroll
    for (int e = 0; e < NE; ++e) {
      float v = acc[e];
#pragma unroll
      for (int off = 32; off; off >>= 1) v += __shfl_down(v, off, 64);
      acc[e] = v;
    }

    if (lane == 0) {
      float v0 = -1e30f, v1 = -1e30f; int i0 = 0, i1 = 0;
#pragma unroll
      for (int e = 0; e < NE; ++e) {
        const float p = acc[e];
        if (p > v0) { v1 = v0; i1 = i0; v0 = p; i0 = e; }
        else if (p > v1) { v1 = p; i1 = e; }
      }
      const float e1 = expf(v1 - v0);
      const float g0 = 1.0f / (1.0f + e1);
      const float g1 = e1 / (1.0f + e1);
      const int p0 = atomicAdd(&counts[i0], 1);
      const int p1 = atomicAdd(&counts[i1], 1);
      ti[2 * t] = i0;  ti[2 * t + 1] = i1;
      tpos[2 * t] = p0; tpos[2 * t + 1] = p1;
      tg[2 * t] = g0;  tg[2 * t + 1] = g1;
    }
  }
}

// ---------------------------------------------------------------------------
// Router stage B: prefix-sum counts -> seg, scatter slots.
// ---------------------------------------------------------------------------
__global__ __launch_bounds__(1024) void router_scatter(
    const int* __restrict__ counts, const int* __restrict__ ti,
    const int* __restrict__ tpos, const float* __restrict__ tg,
    int* __restrict__ tos, float* __restrict__ gos, int* __restrict__ seg)
{
  __shared__ int offs[NE];
  const int t = threadIdx.x;
  if (t == 0) {
    int o = 0;
    for (int e = 0; e < NE; ++e) {
      offs[e] = o; seg[e] = o; seg[NE + e] = counts[e]; o += counts[e];
    }
  }
  __syncthreads();
  const int i0 = ti[2 * t], i1 = ti[2 * t + 1];
  const int s0 = offs[i0] + tpos[2 * t];
  const int s1 = offs[i1] + tpos[2 * t + 1];
  tos[s0] = t; gos[s0] = tg[2 * t];
  tos[s1] = t; gos[s1] = tg[2 * t + 1];
}

// ---------------------------------------------------------------------------
// FFN GEMM core: 128m x 64n tile, BK=64, 4 waves (2x2 over 64x32 each,
// acc 4x2). global_load_lds staging (A:4 + B:2 issues/wave), XOR-swizzled
// unpadded LDS (physical 16B chunk = logical ^ (row&7)).
// ---------------------------------------------------------------------------

// FFN1: h = gelu(x_gather @ w1t[e]) -> hbuf (bf16)
__global__ __launch_bounds__(256) void ffn1_kernel(
    const u16* __restrict__ xb, const u16* __restrict__ w1t,
    const int* __restrict__ tos, const int* __restrict__ seg,
    u16* __restrict__ hbuf)
{
  const int e   = blockIdx.z;
  const int cnt = seg[NE + e];
  const int m0  = blockIdx.y * 128;
  if (m0 >= cnt) return;
  const int start = seg[e];
  const int n0    = blockIdx.x * 64;

  __shared__ __align__(16) u16 As[128 * 64];
  __shared__ __align__(16) u16 Bs[64 * 64];
  __shared__ int toks[128];

  const int tid = threadIdx.x;
  if (tid < 128) toks[tid] = tos[start + min(m0 + tid, cnt - 1)];
  __syncthreads();

  const int lane = tid & 63;
  const int wid  = tid >> 6;
  const int rsub = lane >> 3;           // 0..7
  const int c8   = (lane & 7) ^ rsub;   // logical 16B chunk

  const u16* ag[4]; u16* al[4];
#pragma unroll
  for (int i = 0; i < 4; ++i) {
    const int rb = wid * 8 + i * 32;
    ag[i] = xb + (size_t)toks[rb + rsub] * HD + c8 * 8;
    al[i] = As + rb * 64;
  }
  const u16* bg[2]; u16* bl[2];
#pragma unroll
  for (int i = 0; i < 2; ++i) {
    const int rb = wid * 8 + i * 32;
    bg[i] = w1t + ((size_t)e * FF + n0 + rb + rsub) * HD + c8 * 8;
    bl[i] = Bs + rb * 64;
  }

  const int wm  = (wid >> 1) << 6;      // 0 / 64
  const int wn  = (wid & 1) << 5;       // 0 / 32
  const int q   = lane >> 4;
  const int r16 = lane & 15;

  f32x4 acc[4][2] = {};

  for (int k0 = 0; k0 < HD; k0 += BK) {
#pragma unroll
    for (int i = 0; i < 4; ++i) load16(ag[i] + k0, al[i]);
#pragma unroll
    for (int i = 0; i < 2; ++i) load16(bg[i] + k0, bl[i]);
    __syncthreads();
#pragma unroll
    for (int s = 0; s < 2; ++s) {
      const int pa = ((s << 2) + q) ^ (r16 & 7);
      bf16x8 af[4], bf[2];
#pragma unroll
      for (int t = 0; t < 4; ++t)
        af[t] = *(const bf16x8*)(&As[(wm + t * 16 + r16) * 64 + pa * 8]);
#pragma unroll
      for (int t = 0; t < 2; ++t)
        bf[t] = *(const bf16x8*)(&Bs[(wn + t * 16 + r16) * 64 + pa * 8]);
#pragma unroll
      for (int t = 0; t < 4; ++t)
#pragma unroll
        for (int c = 0; c < 2; ++c)
          acc[t][c] = __builtin_amdgcn_mfma_f32_16x16x32_bf16(af[t], bf[c], acc[t][c], 0, 0, 0);
    }
    __syncthreads();
  }

#pragma unroll
  for (int t = 0; t < 4; ++t) {
    const int mbase = m0 + wm + t * 16 + q * 4;
#pragma unroll
    for (int i = 0; i < 4; ++i) {
      if (mbase + i < cnt) {
        u16* drow = hbuf + (size_t)(start + mbase + i) * FF + n0 + wn;
#pragma unroll
        for (int c = 0; c < 2; ++c) {
          float v = acc[t][c][i];
          v = 0.5f * v * (1.0f + erff(v * 0.70710678118f));
          drow[c * 16 + r16] = f2bf(v);
        }
      }
    }
  }
}

// FFN2: out += gate * (h @ w2t[e]), K-split x4, atomic fp32 accumulate.
#define KSPLIT 4
#define KSEG   (FF / KSPLIT)   // 768

__global__ __launch_bounds__(256) void ffn2_kernel(
    const u16* __restrict__ hbuf, const u16* __restrict__ w2t,
    const int* __restrict__ tos, const float* __restrict__ gos,
    const int* __restrict__ seg, float* __restrict__ out)
{
  const int ez  = blockIdx.z;
  const int e   = ez >> 2;
  const int ks  = ez & 3;
  const int cnt = seg[NE + e];
  const int m0  = blockIdx.y * 128;
  if (m0 >= cnt) return;
  const int start = seg[e];
  const int n0    = blockIdx.x * 64;
  const int kbase = ks * KSEG;

  __shared__ __align__(16) u16 As[128 * 64];
  __shared__ __align__(16) u16 Bs[64 * 64];
  __shared__ int   toks[128];
  __shared__ float gates[128];

  const int tid = threadIdx.x;
  if (tid < 128) {
    const int idx = start + min(m0 + tid, cnt - 1);
    toks[tid]  = tos[idx];
    gates[tid] = gos[idx];
  }
  __syncthreads();

  const int lane = tid & 63;
  const int wid  = tid >> 6;
  const int rsub = lane >> 3;
  const int c8   = (lane & 7) ^ rsub;

  const u16* ag[4]; u16* al[4];
#pragma unroll
  for (int i = 0; i < 4; ++i) {
    const int rb = wid * 8 + i * 32;
    ag[i] = hbuf + (size_t)(start + min(m0 + rb + rsub, cnt - 1)) * FF + kbase + c8 * 8;
    al[i] = As + rb * 64;
  }
  const u16* bg[2]; u16* bl[2];
#pragma unroll
  for (int i = 0; i < 2; ++i) {
    const int rb = wid * 8 + i * 32;
    bg[i] = w2t + ((size_t)e * HD + n0 + rb + rsub) * FF + kbase + c8 * 8;
    bl[i] = Bs + rb * 64;
  }

  const int wm  = (wid >> 1) << 6;
  const int wn  = (wid & 1) << 5;
  const int q   = lane >> 4;
  const int r16 = lane & 15;

  f32x4 acc[4][2] = {};

  for (int k0 = 0; k0 < KSEG; k0 += BK) {
#pragma unroll
    for (int i = 0; i < 4; ++i) load16(ag[i] + k0, al[i]);
#pragma unroll
    for (int i = 0; i < 2; ++i) load16(bg[i] + k0, bl[i]);
    __syncthreads();
#pragma unroll
    for (int s = 0; s < 2; ++s) {
      const int pa = ((s << 2) + q) ^ (r16 & 7);
      bf16x8 af[4], bf[2];
#pragma unroll
      for (int t = 0; t < 4; ++t)
        af[t] = *(const bf16x8*)(&As[(wm + t * 16 + r16) * 64 + pa * 8]);
#pragma unroll
      for (int t = 0; t < 2; ++t)
        bf[t] = *(const bf16x8*)(&Bs[(wn + t * 16 + r16) * 64 + pa * 8]);
#pragma unroll
      for (int t = 0; t < 4; ++t)
#pragma unroll
        for (int c = 0; c < 2; ++c)
          acc[t][c] = __builtin_amdgcn_mfma_f32_16x16x32_bf16(af[t], bf[c], acc[t][c], 0, 0, 0);
    }
    __syncthreads();
  }

#pragma unroll
  for (int t = 0; t < 4; ++t) {
    const int mbase = wm + t * 16 + q * 4;
#pragma unroll
    for (int i = 0; i < 4; ++i) {
      const int mloc = mbase + i;
      if (m0 + mloc < cnt) {
        const int tok  = toks[mloc];
        const float g  = gates[mloc];
        float* drow = out + (size_t)tok * HD + n0 + wn;
#pragma unroll
        for (int c = 0; c < 2; ++c) {
          atomicAdd(drow + c * 16 + r16, g * acc[t][c][i]);
        }
      }
    }
  }
}

// ---------------------------------------------------------------------------
extern "C" void kernel_launch(void* const* d_in, const int* in_sizes, int n_in,
                              void* d_out, int out_size, void* d_ws, size_t ws_size,
                              hipStream_t stream) {
  const float* x  = (const float*)d_in[0];
  const float* rw = (const float*)d_in[1];
  const float* w1 = (const float*)d_in[2];
  const float* w2 = (const float*)d_in[3];
  float* out = (float*)d_out;

  char* ws = (char*)d_ws;
  const size_t o_xb    = 0;
  const size_t o_hbuf  = o_xb + (size_t)NTOK * HD * 2;
  const size_t o_tos   = o_hbuf + (size_t)NSLOT * FF * 2;
  const size_t o_gos   = o_tos + (size_t)NSLOT * 4;
  const size_t o_seg   = o_gos + (size_t)NSLOT * 4;
  const size_t o_cnt   = o_seg + 64 * 4;
  const size_t o_ti    = o_cnt + NE * 4;
  const size_t o_tpos  = o_ti + (size_t)NSLOT * 4;
  const size_t o_tg    = o_tpos + (size_t)NSLOT * 4;
  const size_t o_w1t   = (o_tg + (size_t)NSLOT * 4 + 255) & ~(size_t)255;
  const size_t o_w2t   = o_w1t + (size_t)NE * HD * FF * 2;
  u16*   xb    = (u16*)(ws + o_xb);
  u16*   hbuf  = (u16*)(ws + o_hbuf);
  int*   tos   = (int*)(ws + o_tos);
  float* gos   = (float*)(ws + o_gos);
  int*   seg   = (int*)(ws + o_seg);
  int*   cnts  = (int*)(ws + o_cnt);
  int*   ti    = (int*)(ws + o_ti);
  int*   tpos  = (int*)(ws + o_tpos);
  float* tg    = (float*)(ws + o_tg);
  u16*   w1t   = (u16*)(ws + o_w1t);
  u16*   w2t   = (u16*)(ws + o_w2t);

  hipMemsetAsync(d_out, 0, (size_t)NTOK * HD * sizeof(float), stream);
  hipMemsetAsync(cnts, 0, NE * sizeof(int), stream);
  hipLaunchKernelGGL(convert_router_kernel, dim3(NB_CONV + NTOK / 4), dim3(256), 0, stream,
                     w1, w2, w1t, w2t, x, rw, xb, cnts, ti, tpos, tg);
  hipLaunchKernelGGL(router_scatter, dim3(1), dim3(1024), 0, stream,
                     cnts, ti, tpos, tg, tos, gos, seg);
  hipLaunchKernelGGL(ffn1_kernel, dim3(FF / 64, NTOK / 128, NE), dim3(256), 0, stream,
                     xb, w1t, tos, seg, hbuf);
  hipLaunchKernelGGL(ffn2_kernel, dim3(HD / 64, NTOK / 128, NE * KSPLIT), dim3(256), 0, stream,
                     hbuf, w2t, tos, gos, seg, out);
}